// Round 11
// baseline (349.497 us; speedup 1.0000x reference)
//
#include <hip/hip_runtime.h>
#include <stdint.h>
#include <math.h>

typedef __attribute__((ext_vector_type(8))) short short8;
typedef __attribute__((ext_vector_type(4))) short short4v;
typedef __attribute__((ext_vector_type(4))) float floatx4;
typedef __attribute__((ext_vector_type(2))) float floatx2;
typedef __attribute__((ext_vector_type(4))) double double4v;

#define DEV static __device__ __forceinline__

DEV float bf2f(unsigned short u){ union { unsigned int i; float f; } c; c.i = ((unsigned int)u) << 16; return c.f; }
DEV unsigned short f2bf(float f){ union { float f; unsigned int i; } c; c.f = f; unsigned int u = c.i; u += 0x7fffu + ((u >> 16) & 1u); return (unsigned short)(u >> 16); }

#if defined(__has_builtin)
#if __has_builtin(__builtin_amdgcn_global_load_lds)
#define USE_GLL 1
#endif
#if __has_builtin(__builtin_amdgcn_exp2f) && __has_builtin(__builtin_amdgcn_rcpf)
#define FAST_SILU 1
#endif
#endif
#ifndef USE_GLL
#define USE_GLL 0
#endif
#ifndef FAST_SILU
#define FAST_SILU 0
#endif

// async global->LDS, 16B per lane. ldsbase is wave-uniform; HW writes base + lane*16.
DEV void gll16(const unsigned short* g, unsigned short* ldsbase, int lane){
#if USE_GLL
  __builtin_amdgcn_global_load_lds((const __attribute__((address_space(1))) void*)g,
                                   (__attribute__((address_space(3))) void*)ldsbase, 16, 0, 0);
#else
  *(short8*)(ldsbase + lane * 8) = *(const short8*)g;
#endif
}

DEV float silu(float v){
#if FAST_SILU
  float ex = __builtin_amdgcn_exp2f(v * -1.44269504088896f);
  return v * __builtin_amdgcn_rcpf(1.f + ex);   // rcp err ~1ulp fp32, hidden by bf16 round
#else
  return v / (1.f + __expf(-v));
#endif
}

// -------- transpose tile helper: out_bf16[C][R] = in_f32[R][C] ----------------------------
DEV void transpose_tile(const float* in, unsigned short* out, int R, int C,
                        int bx, int by, int bz, int tid, unsigned short* tile)
{
  const long boff = (long)bz * (long)R * (long)C;
  in += boff; out += boff;
  const int c0 = bx * 64, r0 = by * 64;
  const int rr = tid >> 4;
  const int c4 = (tid & 15) * 4;
#pragma unroll
  for (int i = 0; i < 4; i++){
    int r = rr + i * 16;
    floatx4 v = *(const floatx4*)(in + (long)(r0 + r) * C + c0 + c4);
#pragma unroll
    for (int u = 0; u < 4; u++) tile[r * 68 + c4 + u] = f2bf(v[u]);
  }
  __syncthreads();
#pragma unroll
  for (int i = 0; i < 4; i++){
    int cc = rr + i * 16;
    short4v v;
#pragma unroll
    for (int u = 0; u < 4; u++) v[u] = (short)tile[(c4 + u) * 68 + cc];
    *(short4v*)(out + (long)(c0 + cc) * R + r0 + c4) = v;
  }
}

// -------- fused prep: 4 transposes + fold + xconv + f64-MFMA layout probe -----------------
__global__ __launch_bounds__(256) void k_prep(const float* __restrict__ x,
    const float* __restrict__ choice, const float* __restrict__ w1,
    const float* __restrict__ w2, const float* __restrict__ head,
    const float* __restrict__ merge,
    unsigned short* __restrict__ xb, unsigned short* __restrict__ headT,
    unsigned short* __restrict__ mergeT, unsigned short* __restrict__ w1T,
    unsigned short* __restrict__ w2T, double* __restrict__ W64,
    unsigned int* __restrict__ probe)
{
  __shared__ double buf[1536];   // 12.3 KB: transpose tile (8.7 KB) or fold hrow (12.3 KB)
  unsigned short* tile = (unsigned short*)buf;
  const int id = blockIdx.x, tid = threadIdx.x;
  if (id < 144){
    transpose_tile(head, headT, 768, 768, id % 12, id / 12, 0, tid, tile);
  } else if (id < 288){
    int l = id - 144;
    transpose_tile(merge, mergeT, 768, 768, l % 12, l / 12, 0, tid, tile);
  } else if (id < 576){
    int l = id - 288;
    transpose_tile(w1, w1T, 128, 384, l % 6, (l / 6) % 2, l / 12, tid, tile);
  } else if (id < 864){
    int l = id - 576;
    transpose_tile(w2, w2T, 384, 128, l % 2, (l / 2) % 6, l / 12, tid, tile);
  } else if (id < 1248){
    int l = id - 864;                       // 0..383, fold: 2 d's per block
    const int sub = tid >> 7, lt = tid & 127;
    const int d = l * 2 + sub;
    double* hrow = buf + sub * 768;
    for (int i = lt; i < 768; i += 128) hrow[i] = (double)head[(long)d * 768 + i];
    __syncthreads();
    for (int c = lt; c < 144; c += 128){
      int h = c / 24, e = c % 24;
      double a = 0.0;
      const double* hr = hrow + h * 128;
      const float* ch = choice + e * 128;
#pragma unroll 8
      for (int k = 0; k < 128; k++) a += hr[k] * (double)ch[k];
      W64[(long)d * 144 + c] = a;
    }
  } else if (id < 7392){
    const long l = id - 1248;               // 0..6143
    const long i = (l * 256 + tid) * 4;
    floatx4 v = *(const floatx4*)(x + i);
    short4v o;
#pragma unroll
    for (int u = 0; u < 4; u++) o[u] = (short)f2bf(v[u]);
    *(short4v*)(xb + i) = o;
  } else {
    // ---- f64 MFMA layout probe (1 wave). Layout-agnostic operands:
    // probe1: A-val = lane, B == 1  => D[i][j] = S_A(i) independent of j.
    //   A std (lane=16k+i): S_A = 96+4i (==0 mod 4). A alt (lane=4i+k): 16i+6 (==2 mod 4).
    // probe2: A == 1, B-val = lane  => D[i][j] = S_B(j) -> B flag + true D-col per lane.
    if (tid < 64){
      double4v z = {0.0, 0.0, 0.0, 0.0};
      double4v d1 = __builtin_amdgcn_mfma_f64_16x16x4f64((double)tid, 1.0, z, 0, 0, 0);
      double4v d2 = __builtin_amdgcn_mfma_f64_16x16x4f64(1.0, (double)tid, z, 0, 0, 0);
      const int V0 = (int)d1[0];
      const int Astd = ((V0 & 3) == 0) ? 1 : 0;
      unsigned int rp = 0;
      int V;
      V = (int)d1[0]; rp |= (unsigned int)(Astd ? (V - 96) >> 2 : (V - 6) >> 4);
      V = (int)d1[1]; rp |= (unsigned int)(Astd ? (V - 96) >> 2 : (V - 6) >> 4) << 8;
      V = (int)d1[2]; rp |= (unsigned int)(Astd ? (V - 96) >> 2 : (V - 6) >> 4) << 16;
      V = (int)d1[3]; rp |= (unsigned int)(Astd ? (V - 96) >> 2 : (V - 6) >> 4) << 24;
      const int W0 = (int)d2[0];
      const int Bstd = ((W0 & 3) == 0) ? 1 : 0;
      const int cl = Bstd ? (W0 - 96) >> 2 : (W0 - 6) >> 4;
      probe[tid] = rp;
      probe[64 + tid] = (unsigned int)cl;
      if (tid == 0) probe[128] = (unsigned int)(Astd | (Bstd << 1));
    }
  }
}

// -------- bf16 MFMA GEMM body (BT input), 128x128 tile, BK=64; OUTF=1 -> fp32 C -----------
template<int OUTF>
DEV void gemm_body(const unsigned short* __restrict__ A, const unsigned short* __restrict__ BT,
                   unsigned short* __restrict__ C, float* __restrict__ Cf, int N, int K,
                   unsigned short* As, unsigned short* Bs, int m0, int n0, int tid)
{
  const int lane = tid & 63;
  const int w = tid >> 6;
  const int wy = w >> 1, wx = w & 1;

  floatx4 acc[4][4];
  {
    floatx4 z4 = {0.f, 0.f, 0.f, 0.f};
#pragma unroll
    for (int i = 0; i < 4; i++)
#pragma unroll
      for (int j = 0; j < 4; j++) acc[i][j] = z4;
  }

  const int rsub = lane >> 3;
  const int kcol = (lane & 7) * 8;

  for (int k0 = 0; k0 < K; k0 += 64){
#pragma unroll
    for (int i = 0; i < 4; i++){
      const int inst = w * 4 + i;
      const int rr = inst * 8 + rsub;
      gll16(A + (long)(m0 + rr) * K + k0 + kcol, &As[inst * 512], lane);
      gll16(BT + (long)(n0 + rr) * K + k0 + kcol, &Bs[inst * 512], lane);
    }
    __syncthreads();
#pragma unroll
    for (int ks = 0; ks < 2; ++ks){
      const int kb = ks * 32 + (lane >> 4) * 8;
      short8 af[4], bfr[4];
#pragma unroll
      for (int mi = 0; mi < 4; mi++) af[mi]  = *(const short8*)&As[(wy * 64 + mi * 16 + (lane & 15)) * 64 + kb];
#pragma unroll
      for (int ni = 0; ni < 4; ni++) bfr[ni] = *(const short8*)&Bs[(wx * 64 + ni * 16 + (lane & 15)) * 64 + kb];
#pragma unroll
      for (int mi = 0; mi < 4; mi++)
#pragma unroll
        for (int ni = 0; ni < 4; ni++)
          acc[mi][ni] = __builtin_amdgcn_mfma_f32_16x16x32_bf16(af[mi], bfr[ni], acc[mi][ni], 0, 0, 0);
    }
    __syncthreads();
  }

  const int ml = lane & 15;
  const int rq = (lane >> 4) * 4;
#pragma unroll
  for (int mi = 0; mi < 4; mi++){
    const int rowb = m0 + wy * 64 + mi * 16 + rq;
#pragma unroll
    for (int ni = 0; ni < 4; ni++){
      const int col = n0 + wx * 64 + ni * 16 + ml;
#pragma unroll
      for (int r = 0; r < 4; r++){
        float v = acc[mi][ni][r];
        if (OUTF) Cf[(long)(rowb + r) * N + col] = v;
        else      C[(long)(rowb + r) * N + col] = f2bf(v);
      }
    }
  }
}

// -------- gates via fp64 MFMA, probe-calibrated layouts; 2 K-segments of 384 --------------
// (R11: kseg 4->2 halves P traffic 37.7->18.9 MB; total fp64 MFMA count unchanged, gates
// stay matrix-pipe-bound ~23 us. Summation-order delta ~1e-16 rel, far below selection gaps.)
DEV void gates_mfma(const float* __restrict__ xg, const double* __restrict__ W,
                    double* __restrict__ P, const unsigned int* __restrict__ probe,
                    int id, int tid)
{
  const int lane = tid & 63, w = tid >> 6;
  const unsigned int flags = probe[128];
  const int Astd = (int)(flags & 1u), Bstd = (int)((flags >> 1) & 1u);
  const unsigned int rp = probe[lane];
  const int cl = (int)probe[64 + lane];
  const int ar = Astd ? (lane & 15) : (lane >> 2);   // A row this lane supplies
  const int ak = Astd ? (lane >> 4) : (lane & 3);    // A k-index this lane supplies
  const int bk = Bstd ? (lane >> 4) : (lane & 3);    // B k-index
  const int bj = Bstd ? (lane & 15) : (lane >> 2);   // B col-in-tile

  const int kseg = id >> 7;            // 0..1 K-segments of 384
  const int row0 = (id & 127) * 64 + w * 16;

  double4v acc[9];
#pragma unroll
  for (int t = 0; t < 9; t++) acc[t] = (double4v){0.0, 0.0, 0.0, 0.0};

  const float* arow = xg + (long)(row0 + ar) * 768;
  const int kbase = kseg * 384;
  for (int kc = 0; kc < 384; kc += 4){
    const int k0 = kbase + kc;
    const double a = (double)arow[k0 + ak];
    const double* wr = W + (long)(k0 + bk) * 144 + bj;
#pragma unroll
    for (int t = 0; t < 9; t++)
      acc[t] = __builtin_amdgcn_mfma_f64_16x16x4f64(a, wr[t * 16], acc[t], 0, 0, 0);
  }

  const int r0_ = (int)(rp & 255u), r1_ = (int)((rp >> 8) & 255u);
  const int r2_ = (int)((rp >> 16) & 255u), r3_ = (int)((rp >> 24) & 255u);
  double* dst = P + (long)kseg * 8192 * 144 + (long)row0 * 144;
#pragma unroll
  for (int t = 0; t < 9; t++){
    const int cb = t * 16 + cl;
    dst[(long)r0_ * 144 + cb] = acc[t][0];
    dst[(long)r1_ * 144 + cb] = acc[t][1];
    dst[(long)r2_ * 144 + cb] = acc[t][2];
    dst[(long)r3_ * 144 + cb] = acc[t][3];
  }
}

// -------- fused gates + head-GEMM: [0,256) fp64-MFMA gates, [256,640) bf16 gemm -----------
__global__ __launch_bounds__(256, 4) void k_main0(const unsigned short* __restrict__ xb,
    const unsigned short* __restrict__ headT, unsigned short* __restrict__ x1,
    const float* __restrict__ xg, const double* __restrict__ W, double* __restrict__ P,
    const unsigned int* __restrict__ probe)
{
  __shared__ unsigned short lds[128 * 64 * 2];   // 32 KB: gemm As+Bs; gates uses none
  const int id = blockIdx.x, tid = threadIdx.x;
  if (id < 256){
    gates_mfma(xg, W, P, probe, id, tid);
  } else {
    const int id2 = id - 256;    // 0..383
    unsigned short* As = lds;
    unsigned short* Bs = As + 128 * 64;
    gemm_body<0>(xb, headT, x1, nullptr, 768, 768, As, Bs, (id2 & 63) * 128, (id2 >> 6) * 128, tid);
  }
}

// -------- fused reduce + softmax: logits from 2 partials, softmax, write gatesT[be][n] ----
__global__ __launch_bounds__(256) void k_softmax(const double* __restrict__ P,
                                                 double* __restrict__ gatesT)
{
  const int gid = blockIdx.x * 256 + threadIdx.x;   // < 49152
  const int R = gid / 6, h = gid % 6;
  const int b = R >> 10, s = R & 1023;
  const int n = s * 6 + h;
  const long S = (long)8192 * 144;
  const long base = (long)R * 144 + h * 24;
  double l[24];
#pragma unroll
  for (int e = 0; e < 24; e++){
    const long o = base + e;
    l[e] = P[o] + P[S + o];
  }
  double m = l[0];
#pragma unroll
  for (int e = 1; e < 24; e++) m = fmax(m, l[e]);
  double ssum = 0.0;
#pragma unroll
  for (int e = 0; e < 24; e++){ l[e] = exp(l[e] - m); ssum += l[e]; }
  double is = 1.0 / ssum;
#pragma unroll
  for (int e = 0; e < 24; e++)
    gatesT[((long)(b * 24 + e)) * 6144 + n] = l[e] * is;
}

// -------- top-K=1024 of 6144 per (b,e), exact fp64, jax tie semantics ---------------------
// R11: single-barrier block reduce via parity double-buffer (round k+2's write to buf p can
// only happen after round k+1's sync, which waits for all round-k readers of buf p).
DEV int blk_reduce(int v, volatile int* sbuf, int tid, int ph){
#pragma unroll
  for (int off = 32; off > 0; off >>= 1) v += __shfl_down(v, off);
  volatile int* sb = sbuf + (ph & 1) * 4;
  if ((tid & 63) == 0) sb[tid >> 6] = v;
  __syncthreads();
  return sb[0] + sb[1] + sb[2] + sb[3];
}

__global__ __launch_bounds__(256) void k_topk(const double* __restrict__ gatesT,
                                              int* __restrict__ Kidx, float* __restrict__ Gval,
                                              int* __restrict__ cnt, unsigned short* __restrict__ inv)
{
  __shared__ int sbuf[8];
  __shared__ int s_pos;
  __shared__ unsigned long long mm[8];
  const int tid = threadIdx.x;
  const int be = blockIdx.x;
  const int b = be / 24, e = be % 24;
  const double* g = gatesT + (long)be * 6144;
  int ph = 0;

  unsigned long long key[24];
#pragma unroll
  for (int j = 0; j < 24; j++)
    key[j] = (unsigned long long)__double_as_longlong(g[tid + 256 * j]);

  // seed binary search with block min/max: lo = min-1, hi = max preserves the invariant
  // count(>lo) >= 1024 > count(>hi).
  unsigned long long mn = key[0], mx = key[0];
#pragma unroll
  for (int j = 1; j < 24; j++){
    mn = key[j] < mn ? key[j] : mn;
    mx = key[j] > mx ? key[j] : mx;
  }
#pragma unroll
  for (int off = 32; off > 0; off >>= 1){
    unsigned long long a = (unsigned long long)__shfl_down((long long)mn, off);
    unsigned long long c = (unsigned long long)__shfl_down((long long)mx, off);
    mn = a < mn ? a : mn;
    mx = c > mx ? c : mx;
  }
  if ((tid & 63) == 0){ mm[(tid >> 6) * 2] = mn; mm[(tid >> 6) * 2 + 1] = mx; }
  __syncthreads();
  mn = mm[0]; mx = mm[1];
#pragma unroll
  for (int q = 1; q < 4; q++){
    mn = mm[2 * q] < mn ? mm[2 * q] : mn;
    mx = mm[2 * q + 1] > mx ? mm[2 * q + 1] : mx;
  }

  unsigned long long lo = mn - 1ull, hi = mx;
  for (int it = 0; it < 64; ++it){
    if (hi - lo <= 1ull) break;
    unsigned long long mid = lo + ((hi - lo) >> 1);
    int c = 0;
#pragma unroll
    for (int j = 0; j < 24; j++) c += (key[j] > mid) ? 1 : 0;
    c = blk_reduce(c, sbuf, tid, ph++);
    if (c >= 1024) lo = mid; else hi = mid;
  }
  const unsigned long long T = hi;
  int cg = 0;
#pragma unroll
  for (int j = 0; j < 24; j++) cg += (key[j] > T) ? 1 : 0;
  cg = blk_reduce(cg, sbuf, tid, ph++);
  const int need = 1024 - cg;

  int lo2 = 0, hi2 = 6144;
  for (int it = 0; it < 13; ++it){
    if (hi2 - lo2 <= 1) break;
    int mid = (lo2 + hi2) >> 1;
    int c = 0;
#pragma unroll
    for (int j = 0; j < 24; j++) c += (key[j] == T && (tid + 256 * j) < mid) ? 1 : 0;
    c = blk_reduce(c, sbuf, tid, ph++);
    if (c >= need) hi2 = mid; else lo2 = mid;
  }
  const int m = hi2;

  if (tid == 0) s_pos = 0;
  __syncthreads();
#pragma unroll
  for (int j = 0; j < 24; j++){
    int n = tid + 256 * j;
    bool sel = (key[j] > T) || (key[j] == T && n < m);
    if (sel){
      int slot = atomicAdd(&s_pos, 1);
      Kidx[(long)be * 1024 + slot] = n;
      Gval[(long)be * 1024 + slot] = (float)__longlong_as_double((long long)key[j]);
      int t = b * 6144 + n;
      int p = atomicAdd(&cnt[t], 1);
      inv[(long)t * 24 + p] = (unsigned short)(e * 1024 + slot);
    }
  }
}

// -------- merge GEMM (fp32 out) -----------------------------------------------------------
__global__ __launch_bounds__(256, 2) void k_gemm2(const unsigned short* __restrict__ A,
    const unsigned short* __restrict__ BT, float* __restrict__ Cf)
{
  __shared__ unsigned short As[128 * 64];
  __shared__ unsigned short Bs[128 * 64];
  gemm_body<1>(A, BT, nullptr, Cf, 768, 768, As, Bs,
               (int)blockIdx.x * 128, (int)blockIdx.y * 128, (int)threadIdx.x);
}

// -------- fused per-expert FFN: Y[be][k][dh] = gate * (silu(gather(x1)@w1) @ w2), bf16 ----
// grid (16 m-tiles of 64 rows, 192 be). block 256. A-tile in registers (16 VGPR/lane).
// LDS 40960 B exactly -> 4 blocks/CU (160 KiB); launch_bounds(256,4) keeps VGPR <= 128.
// R4 structure, measured 70-71 us; established local optimum (R5-R8: LDS-read amplification
// binds; re-tilings hit VGPR/occupancy wall or global-fragment coalescing wall). FROZEN.
__global__ __launch_bounds__(256, 4) void k_ffn(const unsigned short* __restrict__ x1,
    const unsigned short* __restrict__ w1T, const unsigned short* __restrict__ w2T,
    const int* __restrict__ KidxAll, const float* __restrict__ GvalAll,
    unsigned short* __restrict__ Y)
{
  __shared__ unsigned short W1c[64 * 128];   // 16 KB [hcol][k]
  __shared__ unsigned short W2c[128 * 64];   // 16 KB [out][hchunk]
  __shared__ unsigned short Hc[64 * 64];     //  8 KB [tokrow][hcol]
  const int tid = threadIdx.x, lane = tid & 63, w = tid >> 6;
  const int tx = lane & 15, quad = lane >> 4;
  const int mt = blockIdx.x;                 // 0..15, 64-token tiles
  const int be = blockIdx.y;
  const int b = be / 24, e = be % 24;
  const int* idx = KidxAll + (long)be * 1024 + mt * 64;
  const float* scl = GvalAll + (long)be * 1024 + mt * 64;
  const unsigned short* A   = x1  + (long)b * 6144 * 128;
  const unsigned short* w1e = w1T + (long)e * 384 * 128;
  const unsigned short* w2e = w2T + (long)e * 128 * 384;

  // A-fragments direct to registers: afr[ks] = A[idx[w*16+tx]][ks*32+quad*8 ..+8]
  short8 afr[4];
  {
    const int r0 = idx[w * 16 + tx];
    const unsigned short* a0 = A + (long)r0 * 128 + quad * 8;
#pragma unroll
    for (int ks = 0; ks < 4; ks++) afr[ks] = *(const short8*)(a0 + ks * 32);
  }

  floatx4 Yt[2][4];   // [mf out-tile][nf tokrow-tile]
  {
    floatx4 z4 = {0.f, 0.f, 0.f, 0.f};
#pragma unroll
    for (int i = 0; i < 2; i++)
#pragma unroll
      for (int j = 0; j < 4; j++) Yt[i][j] = z4;
  }

  for (int nc = 0; nc < 6; ++nc){
    {
      const int r0 = w * 16;
#pragma unroll
      for (int i = 0; i < 4; i++){
        int lr = r0 + i * 4 + quad;
        int c = tx ^ (lr & 15);
        gll16(w1e + (long)(nc * 64 + lr) * 128 + c * 8, &W1c[(r0 + i * 4) * 128], lane);
      }
    }
    {
      const int r0 = w * 32;
#pragma unroll
      for (int i = 0; i < 4; i++){
        int rr = r0 + i * 8 + (lane >> 3);
        int c = (lane & 7) ^ (rr & 7);
        gll16(w2e + (long)rr * 384 + nc * 64 + c * 8, &W2c[(r0 + i * 8) * 64], lane);
      }
    }
    __syncthreads();

    // stage1: h = silu(A_regs @ W1c^T); wave w -> rows w*16..+16 x 64 hcols (4 nf)
    floatx4 h4[4];
    {
      floatx4 z4 = {0.f, 0.f, 0.f, 0.f};
#pragma unroll
      for (int j = 0; j < 4; j++) h4[j] = z4;
    }
#pragma unroll
    for (int ks = 0; ks < 4; ++ks){
      const int chunk = ks * 4 + quad;
      const int pos = chunk ^ tx;
#pragma unroll
      for (int nf = 0; nf < 4; ++nf){
        short8 bfr = *(const short8*)&W1c[(nf * 16 + tx) * 128 + pos * 8];
        h4[nf] = __builtin_amdgcn_mfma_f32_16x16x32_bf16(afr[ks], bfr, h4[nf], 0, 0, 0);
      }
    }
#pragma unroll
    for (int nf = 0; nf < 4; ++nf){
      const int hchunk = nf * 2 + (tx >> 3);
      const int hoff = tx & 7;
#pragma unroll
      for (int r = 0; r < 4; r++){
        float v = silu(h4[nf][r]);
        const int trow = w * 16 + quad * 4 + r;
        Hc[trow * 64 + (hchunk ^ (trow & 7)) * 8 + hoff] = f2bf(v);
      }
    }
    __syncthreads();

    // stage2: YT[out][tokrow] += W2c[out][hcol] x Hc[tokrow][hcol]; wave w -> outs w*32..+32
#pragma unroll
    for (int ks = 0; ks < 2; ++ks){
      const int chunk2 = ks * 4 + quad;
      const int posx = chunk2 ^ (tx & 7);
      short8 a2[2], b2[4];
#pragma unroll
      for (int mf = 0; mf < 2; ++mf)
        a2[mf] = *(const short8*)&W2c[(w * 32 + mf * 16 + tx) * 64 + posx * 8];
#pragma unroll
      for (int nf = 0; nf < 4; ++nf)
        b2[nf] = *(const short8*)&Hc[(nf * 16 + tx) * 64 + posx * 8];
#pragma unroll
      for (int mf = 0; mf < 2; ++mf)
#pragma unroll
        for (int nf = 0; nf < 4; ++nf)
          Yt[mf][nf] = __builtin_amdgcn_mfma_f32_16x16x32_bf16(a2[mf], b2[nf], Yt[mf][nf], 0, 0, 0);
    }
    __syncthreads();
  }

#pragma unroll
  for (int nf = 0; nf < 4; ++nf){
    const int rb = nf * 16 + tx;
    const float g = scl[rb];
    unsigned short* dst = Y + ((long)be * 1024 + mt * 64 + rb) * 128 + w * 32 + quad * 4;
#pragma unroll
    for (int mf = 0; mf < 2; ++mf){
      short4v v;
#pragma unroll
      for (int r = 0; r < 4; r++) v[r] = (short)f2bf(Yt[mf][nf][r] * g);
      *(short4v*)(dst + mf * 16) = v;
    }
  }
}

// -------- combine: xout[t][:] = sum over picks of Y[e][slot][:] (gates pre-applied) -------
// R11: 4-way unrolled pick loop; inv codes loaded as one u64, Y-row dword loads issued
// independently (MLP) instead of the serial inv->Y dependent chain per pick.
__global__ __launch_bounds__(256) void k_combine(const int* __restrict__ cnt,
    const unsigned short* __restrict__ inv, const unsigned short* __restrict__ Y,
    unsigned short* __restrict__ xout)
{
  const int t = blockIdx.x * 4 + (threadIdx.x >> 6);   // token id, < 49152
  const int lane = threadIdx.x & 63;
  const int b = t / 6144;
  const int c = cnt[t];
  const unsigned short* ivp = inv + (long)t * 24;
  const unsigned short* Yb = Y + ((long)(b * 24) << 17);   // + code<<7 selects the row
  float a0 = 0.f, a1 = 0.f;
  int p = 0;
  for (; p + 4 <= c; p += 4){
    unsigned long long iv = *(const unsigned long long*)(ivp + p);   // t*48+2p: 8B-aligned
    const int c0 = (int)(iv & 0xffffu), c1 = (int)((iv >> 16) & 0xffffu);
    const int c2 = (int)((iv >> 32) & 0xffffu), c3 = (int)(iv >> 48);
    unsigned int v0 = *(const unsigned int*)(Yb + (((long)c0) << 7) + lane * 2);
    unsigned int v1 = *(const unsigned int*)(Yb + (((long)c1) << 7) + lane * 2);
    unsigned int v2 = *(const unsigned int*)(Yb + (((long)c2) << 7) + lane * 2);
    unsigned int v3 = *(const unsigned int*)(Yb + (((long)c3) << 7) + lane * 2);
    a0 += bf2f((unsigned short)v0); a1 += bf2f((unsigned short)(v0 >> 16));
    a0 += bf2f((unsigned short)v1); a1 += bf2f((unsigned short)(v1 >> 16));
    a0 += bf2f((unsigned short)v2); a1 += bf2f((unsigned short)(v2 >> 16));
    a0 += bf2f((unsigned short)v3); a1 += bf2f((unsigned short)(v3 >> 16));
  }
  for (; p < c; ++p){
    const int code = ivp[p];
    unsigned int v = *(const unsigned int*)(Yb + (((long)code) << 7) + lane * 2);
    a0 += bf2f((unsigned short)v); a1 += bf2f((unsigned short)(v >> 16));
  }
  unsigned short* o = xout + ((long)t << 7) + lane * 2;
  o[0] = f2bf(a0); o[1] = f2bf(a1);
}

// ==========================================================================================
extern "C" void kernel_launch(void* const* d_in, const int* in_sizes, int n_in,
                              void* d_out, int out_size, void* d_ws, size_t ws_size,
                              hipStream_t stream)
{
  const float* x      = (const float*)d_in[0];
  const float* choice = (const float*)d_in[1];
  const float* w1     = (const float*)d_in[2];
  const float* w2     = (const float*)d_in[3];
  const float* head   = (const float*)d_in[4];
  const float* merge  = (const float*)d_in[5];
  float* out = (float*)d_out;
  (void)in_sizes; (void)n_in; (void)out_size; (void)ws_size;

  char* p = (char*)d_ws;
  auto alloc = [&p](size_t bytes) -> void* {
    void* q = (void*)p; p += (bytes + 255) & ~(size_t)255; return q;
  };

  unsigned short* headT = (unsigned short*)alloc((size_t)768 * 768 * 2);
  unsigned short* mergeT= (unsigned short*)alloc((size_t)768 * 768 * 2);
  unsigned short* w1T   = (unsigned short*)alloc((size_t)24 * 384 * 128 * 2);
  unsigned short* w2T   = (unsigned short*)alloc((size_t)24 * 128 * 384 * 2);
  double* W64           = (double*)alloc((size_t)768 * 144 * 8);
  int* Kidx             = (int*)alloc((size_t)192 * 1024 * 4);
  float* Gval           = (float*)alloc((size_t)192 * 1024 * 4);
  int* cnt              = (int*)alloc((size_t)49152 * 4);
  unsigned short* inv   = (unsigned short*)alloc((size_t)49152 * 24 * 2);
  unsigned short* xb    = (unsigned short*)alloc((size_t)8192 * 768 * 2);   // 12.58 MB
  unsigned short* x1    = (unsigned short*)alloc((size_t)8192 * 768 * 2);   // 12.58 MB
  // big region (50.33 MB): Y for ffn; before topk it hosts P (18.87) + gatesT (9.44)
  unsigned short* Y     = (unsigned short*)alloc((size_t)192 * 1024 * 128 * 2);
  double* P             = (double*)Y;                                             // [2][8192][144]
  double* gatesT        = (double*)((char*)Y + (size_t)2 * 8192 * 144 * 8);       // 9.44 MB
  unsigned short* xout  = xb;            // xb dead after k_main0; xout written by combine
  // probe (516 B) aliases Kidx: written by k_prep, read by k_main0, dead before k_topk.
  unsigned int* probe   = (unsigned int*)Kidx;

  hipMemsetAsync(cnt, 0, (size_t)49152 * 4, stream);
  k_prep<<<dim3(7393), 256, 0, stream>>>(x, choice, w1, w2, head, merge,
                                         xb, headT, mergeT, w1T, w2T, W64, probe);
  k_main0<<<dim3(640), 256, 0, stream>>>(xb, headT, x1, x, W64, P, probe);
  k_softmax<<<dim3(192), 256, 0, stream>>>(P, gatesT);
  k_topk<<<dim3(192), 256, 0, stream>>>(gatesT, Kidx, Gval, cnt, inv);
  // P/gatesT dead; Y region free for ffn
  k_ffn<<<dim3(16, 192, 1), 256, 0, stream>>>(x1, w1T, w2T, Kidx, Gval, Y);
  k_combine<<<dim3(12288), 256, 0, stream>>>(cnt, inv, Y, xout);
  k_gemm2<<<dim3(64, 6, 1), 256, 0, stream>>>(xout, mergeT, out);
}

// Round 12
// 329.048 us; speedup vs baseline: 1.0621x; 1.0621x over previous
//
#include <hip/hip_runtime.h>
#include <stdint.h>
#include <math.h>

typedef __attribute__((ext_vector_type(8))) short short8;
typedef __attribute__((ext_vector_type(4))) short short4v;
typedef __attribute__((ext_vector_type(4))) float floatx4;
typedef __attribute__((ext_vector_type(2))) float floatx2;
typedef __attribute__((ext_vector_type(4))) double double4v;

#define DEV static __device__ __forceinline__

DEV float bf2f(unsigned short u){ union { unsigned int i; float f; } c; c.i = ((unsigned int)u) << 16; return c.f; }
DEV unsigned short f2bf(float f){ union { float f; unsigned int i; } c; c.f = f; unsigned int u = c.i; u += 0x7fffu + ((u >> 16) & 1u); return (unsigned short)(u >> 16); }

#if defined(__has_builtin)
#if __has_builtin(__builtin_amdgcn_global_load_lds)
#define USE_GLL 1
#endif
#if __has_builtin(__builtin_amdgcn_exp2f) && __has_builtin(__builtin_amdgcn_rcpf)
#define FAST_SILU 1
#endif
#endif
#ifndef USE_GLL
#define USE_GLL 0
#endif
#ifndef FAST_SILU
#define FAST_SILU 0
#endif

// async global->LDS, 16B per lane. ldsbase is wave-uniform; HW writes base + lane*16.
DEV void gll16(const unsigned short* g, unsigned short* ldsbase, int lane){
#if USE_GLL
  __builtin_amdgcn_global_load_lds((const __attribute__((address_space(1))) void*)g,
                                   (__attribute__((address_space(3))) void*)ldsbase, 16, 0, 0);
#else
  *(short8*)(ldsbase + lane * 8) = *(const short8*)g;
#endif
}

DEV float silu(float v){
#if FAST_SILU
  float ex = __builtin_amdgcn_exp2f(v * -1.44269504088896f);
  return v * __builtin_amdgcn_rcpf(1.f + ex);   // rcp err ~1ulp fp32, hidden by bf16 round
#else
  return v / (1.f + __expf(-v));
#endif
}

// -------- transpose tile helper: out_bf16[C][R] = in_f32[R][C] ----------------------------
DEV void transpose_tile(const float* in, unsigned short* out, int R, int C,
                        int bx, int by, int bz, int tid, unsigned short* tile)
{
  const long boff = (long)bz * (long)R * (long)C;
  in += boff; out += boff;
  const int c0 = bx * 64, r0 = by * 64;
  const int rr = tid >> 4;
  const int c4 = (tid & 15) * 4;
#pragma unroll
  for (int i = 0; i < 4; i++){
    int r = rr + i * 16;
    floatx4 v = *(const floatx4*)(in + (long)(r0 + r) * C + c0 + c4);
#pragma unroll
    for (int u = 0; u < 4; u++) tile[r * 68 + c4 + u] = f2bf(v[u]);
  }
  __syncthreads();
#pragma unroll
  for (int i = 0; i < 4; i++){
    int cc = rr + i * 16;
    short4v v;
#pragma unroll
    for (int u = 0; u < 4; u++) v[u] = (short)tile[(c4 + u) * 68 + cc];
    *(short4v*)(out + (long)(c0 + cc) * R + r0 + c4) = v;
  }
}

// -------- fused prep: 4 transposes + fold + xconv + f64-MFMA layout probe -----------------
__global__ __launch_bounds__(256) void k_prep(const float* __restrict__ x,
    const float* __restrict__ choice, const float* __restrict__ w1,
    const float* __restrict__ w2, const float* __restrict__ head,
    const float* __restrict__ merge,
    unsigned short* __restrict__ xb, unsigned short* __restrict__ headT,
    unsigned short* __restrict__ mergeT, unsigned short* __restrict__ w1T,
    unsigned short* __restrict__ w2T, double* __restrict__ W64,
    unsigned int* __restrict__ probe)
{
  __shared__ double buf[1536];   // 12.3 KB: transpose tile (8.7 KB) or fold hrow (12.3 KB)
  unsigned short* tile = (unsigned short*)buf;
  const int id = blockIdx.x, tid = threadIdx.x;
  if (id < 144){
    transpose_tile(head, headT, 768, 768, id % 12, id / 12, 0, tid, tile);
  } else if (id < 288){
    int l = id - 144;
    transpose_tile(merge, mergeT, 768, 768, l % 12, l / 12, 0, tid, tile);
  } else if (id < 576){
    int l = id - 288;
    transpose_tile(w1, w1T, 128, 384, l % 6, (l / 6) % 2, l / 12, tid, tile);
  } else if (id < 864){
    int l = id - 576;
    transpose_tile(w2, w2T, 384, 128, l % 2, (l / 2) % 6, l / 12, tid, tile);
  } else if (id < 1248){
    int l = id - 864;                       // 0..383, fold: 2 d's per block
    const int sub = tid >> 7, lt = tid & 127;
    const int d = l * 2 + sub;
    double* hrow = buf + sub * 768;
    for (int i = lt; i < 768; i += 128) hrow[i] = (double)head[(long)d * 768 + i];
    __syncthreads();
    for (int c = lt; c < 144; c += 128){
      int h = c / 24, e = c % 24;
      double a = 0.0;
      const double* hr = hrow + h * 128;
      const float* ch = choice + e * 128;
#pragma unroll 8
      for (int k = 0; k < 128; k++) a += hr[k] * (double)ch[k];
      W64[(long)d * 144 + c] = a;
    }
  } else if (id < 7392){
    const long l = id - 1248;               // 0..6143
    const long i = (l * 256 + tid) * 4;
    floatx4 v = *(const floatx4*)(x + i);
    short4v o;
#pragma unroll
    for (int u = 0; u < 4; u++) o[u] = (short)f2bf(v[u]);
    *(short4v*)(xb + i) = o;
  } else {
    // ---- f64 MFMA layout probe (1 wave). Layout-agnostic operands:
    // probe1: A-val = lane, B == 1  => D[i][j] = S_A(i) independent of j.
    //   A std (lane=16k+i): S_A = 96+4i (==0 mod 4). A alt (lane=4i+k): 16i+6 (==2 mod 4).
    // probe2: A == 1, B-val = lane  => D[i][j] = S_B(j) -> B flag + true D-col per lane.
    if (tid < 64){
      double4v z = {0.0, 0.0, 0.0, 0.0};
      double4v d1 = __builtin_amdgcn_mfma_f64_16x16x4f64((double)tid, 1.0, z, 0, 0, 0);
      double4v d2 = __builtin_amdgcn_mfma_f64_16x16x4f64(1.0, (double)tid, z, 0, 0, 0);
      const int V0 = (int)d1[0];
      const int Astd = ((V0 & 3) == 0) ? 1 : 0;
      unsigned int rp = 0;
      int V;
      V = (int)d1[0]; rp |= (unsigned int)(Astd ? (V - 96) >> 2 : (V - 6) >> 4);
      V = (int)d1[1]; rp |= (unsigned int)(Astd ? (V - 96) >> 2 : (V - 6) >> 4) << 8;
      V = (int)d1[2]; rp |= (unsigned int)(Astd ? (V - 96) >> 2 : (V - 6) >> 4) << 16;
      V = (int)d1[3]; rp |= (unsigned int)(Astd ? (V - 96) >> 2 : (V - 6) >> 4) << 24;
      const int W0 = (int)d2[0];
      const int Bstd = ((W0 & 3) == 0) ? 1 : 0;
      const int cl = Bstd ? (W0 - 96) >> 2 : (W0 - 6) >> 4;
      probe[tid] = rp;
      probe[64 + tid] = (unsigned int)cl;
      if (tid == 0) probe[128] = (unsigned int)(Astd | (Bstd << 1));
    }
  }
}

// -------- bf16 MFMA GEMM body (BT input), 128x128 tile, BK=64; OUTF=1 -> fp32 C -----------
template<int OUTF>
DEV void gemm_body(const unsigned short* __restrict__ A, const unsigned short* __restrict__ BT,
                   unsigned short* __restrict__ C, float* __restrict__ Cf, int N, int K,
                   unsigned short* As, unsigned short* Bs, int m0, int n0, int tid)
{
  const int lane = tid & 63;
  const int w = tid >> 6;
  const int wy = w >> 1, wx = w & 1;

  floatx4 acc[4][4];
  {
    floatx4 z4 = {0.f, 0.f, 0.f, 0.f};
#pragma unroll
    for (int i = 0; i < 4; i++)
#pragma unroll
      for (int j = 0; j < 4; j++) acc[i][j] = z4;
  }

  const int rsub = lane >> 3;
  const int kcol = (lane & 7) * 8;

  for (int k0 = 0; k0 < K; k0 += 64){
#pragma unroll
    for (int i = 0; i < 4; i++){
      const int inst = w * 4 + i;
      const int rr = inst * 8 + rsub;
      gll16(A + (long)(m0 + rr) * K + k0 + kcol, &As[inst * 512], lane);
      gll16(BT + (long)(n0 + rr) * K + k0 + kcol, &Bs[inst * 512], lane);
    }
    __syncthreads();
#pragma unroll
    for (int ks = 0; ks < 2; ++ks){
      const int kb = ks * 32 + (lane >> 4) * 8;
      short8 af[4], bfr[4];
#pragma unroll
      for (int mi = 0; mi < 4; mi++) af[mi]  = *(const short8*)&As[(wy * 64 + mi * 16 + (lane & 15)) * 64 + kb];
#pragma unroll
      for (int ni = 0; ni < 4; ni++) bfr[ni] = *(const short8*)&Bs[(wx * 64 + ni * 16 + (lane & 15)) * 64 + kb];
#pragma unroll
      for (int mi = 0; mi < 4; mi++)
#pragma unroll
        for (int ni = 0; ni < 4; ni++)
          acc[mi][ni] = __builtin_amdgcn_mfma_f32_16x16x32_bf16(af[mi], bfr[ni], acc[mi][ni], 0, 0, 0);
    }
    __syncthreads();
  }

  const int ml = lane & 15;
  const int rq = (lane >> 4) * 4;
#pragma unroll
  for (int mi = 0; mi < 4; mi++){
    const int rowb = m0 + wy * 64 + mi * 16 + rq;
#pragma unroll
    for (int ni = 0; ni < 4; ni++){
      const int col = n0 + wx * 64 + ni * 16 + ml;
#pragma unroll
      for (int r = 0; r < 4; r++){
        float v = acc[mi][ni][r];
        if (OUTF) Cf[(long)(rowb + r) * N + col] = v;
        else      C[(long)(rowb + r) * N + col] = f2bf(v);
      }
    }
  }
}

// -------- gates via fp64 MFMA, probe-calibrated layouts; 4 K-segments of 192 --------------
// R12: K remap for vector A-loads. For each 16-K block, instruction i (i=0..3) takes global
// k = k0 + slot*4 + i (slot = probed ak for A-lane, bk for B-lane; same sigma on both sides,
// covers all 16 k's exactly once) -> lane loads ONE float4 per 16 K instead of 4 scalars.
// fp64 sum reorder ~1e-16 rel, far below top-k selection gaps.
DEV void gates_mfma(const float* __restrict__ xg, const double* __restrict__ W,
                    double* __restrict__ P, const unsigned int* __restrict__ probe,
                    int id, int tid)
{
  const int lane = tid & 63, w = tid >> 6;
  const unsigned int flags = probe[128];
  const int Astd = (int)(flags & 1u), Bstd = (int)((flags >> 1) & 1u);
  const unsigned int rp = probe[lane];
  const int cl = (int)probe[64 + lane];
  const int ar = Astd ? (lane & 15) : (lane >> 2);   // A row this lane supplies
  const int ak = Astd ? (lane >> 4) : (lane & 3);    // A k-slot this lane supplies
  const int bk = Bstd ? (lane >> 4) : (lane & 3);    // B k-slot
  const int bj = Bstd ? (lane & 15) : (lane >> 2);   // B col-in-tile

  const int kseg = id >> 7;            // 0..3 K-segments of 192
  const int row0 = (id & 127) * 64 + w * 16;

  double4v acc[9];
#pragma unroll
  for (int t = 0; t < 9; t++) acc[t] = (double4v){0.0, 0.0, 0.0, 0.0};

  const float* arow = xg + (long)(row0 + ar) * 768;
  const int kbase = kseg * 192;
  for (int kb = 0; kb < 192; kb += 16){
    const int k0 = kbase + kb;
    floatx4 av = *(const floatx4*)(arow + k0 + ak * 4);
#pragma unroll
    for (int i = 0; i < 4; i++){
      const double a = (double)av[i];
      const double* wr = W + (long)(k0 + bk * 4 + i) * 144 + bj;
#pragma unroll
      for (int t = 0; t < 9; t++)
        acc[t] = __builtin_amdgcn_mfma_f64_16x16x4f64(a, wr[t * 16], acc[t], 0, 0, 0);
    }
  }

  const int r0_ = (int)(rp & 255u), r1_ = (int)((rp >> 8) & 255u);
  const int r2_ = (int)((rp >> 16) & 255u), r3_ = (int)((rp >> 24) & 255u);
  double* dst = P + (long)kseg * 8192 * 144 + (long)row0 * 144;
#pragma unroll
  for (int t = 0; t < 9; t++){
    const int cb = t * 16 + cl;
    dst[(long)r0_ * 144 + cb] = acc[t][0];
    dst[(long)r1_ * 144 + cb] = acc[t][1];
    dst[(long)r2_ * 144 + cb] = acc[t][2];
    dst[(long)r3_ * 144 + cb] = acc[t][3];
  }
}

// -------- fused gates + head-GEMM: [0,512) fp64-MFMA gates, [512,896) bf16 gemm -----------
// (R12: reverted to kseg=4 / 512 gates blocks — R11's kseg=2 halved gates TLP to ~1
// wave/SIMD and exposed the A-load latency: k_main0 83 us, MfmaUtil 31%.)
__global__ __launch_bounds__(256, 4) void k_main0(const unsigned short* __restrict__ xb,
    const unsigned short* __restrict__ headT, unsigned short* __restrict__ x1,
    const float* __restrict__ xg, const double* __restrict__ W, double* __restrict__ P,
    const unsigned int* __restrict__ probe)
{
  __shared__ unsigned short lds[128 * 64 * 2];   // 32 KB: gemm As+Bs; gates uses none
  const int id = blockIdx.x, tid = threadIdx.x;
  if (id < 512){
    gates_mfma(xg, W, P, probe, id, tid);
  } else {
    const int id2 = id - 512;    // 0..383
    unsigned short* As = lds;
    unsigned short* Bs = As + 128 * 64;
    gemm_body<0>(xb, headT, x1, nullptr, 768, 768, As, Bs, (id2 & 63) * 128, (id2 >> 6) * 128, tid);
  }
}

// -------- fused reduce + softmax: logits from 4 partials, softmax, write gatesT[be][n] ----
__global__ __launch_bounds__(256) void k_softmax(const double* __restrict__ P,
                                                 double* __restrict__ gatesT)
{
  const int gid = blockIdx.x * 256 + threadIdx.x;   // < 49152
  const int R = gid / 6, h = gid % 6;
  const int b = R >> 10, s = R & 1023;
  const int n = s * 6 + h;
  const long S = (long)8192 * 144;
  const long base = (long)R * 144 + h * 24;
  double l[24];
#pragma unroll
  for (int e = 0; e < 24; e++){
    const long o = base + e;
    l[e] = (P[o] + P[S + o]) + (P[2 * S + o] + P[3 * S + o]);
  }
  double m = l[0];
#pragma unroll
  for (int e = 1; e < 24; e++) m = fmax(m, l[e]);
  double ssum = 0.0;
#pragma unroll
  for (int e = 0; e < 24; e++){ l[e] = exp(l[e] - m); ssum += l[e]; }
  double is = 1.0 / ssum;
#pragma unroll
  for (int e = 0; e < 24; e++)
    gatesT[((long)(b * 24 + e)) * 6144 + n] = l[e] * is;
}

// -------- top-K=1024 of 6144 per (b,e), exact fp64, jax tie semantics ---------------------
// Single-barrier block reduce via parity double-buffer (round k+2's write to buf p can
// only happen after round k+1's sync, which waits for all round-k readers of buf p).
DEV int blk_reduce(int v, volatile int* sbuf, int tid, int ph){
#pragma unroll
  for (int off = 32; off > 0; off >>= 1) v += __shfl_down(v, off);
  volatile int* sb = sbuf + (ph & 1) * 4;
  if ((tid & 63) == 0) sb[tid >> 6] = v;
  __syncthreads();
  return sb[0] + sb[1] + sb[2] + sb[3];
}

__global__ __launch_bounds__(256) void k_topk(const double* __restrict__ gatesT,
                                              int* __restrict__ Kidx, float* __restrict__ Gval,
                                              int* __restrict__ cnt, unsigned short* __restrict__ inv)
{
  __shared__ int sbuf[8];
  __shared__ int s_pos;
  __shared__ unsigned long long mm[8];
  const int tid = threadIdx.x;
  const int be = blockIdx.x;
  const int b = be / 24, e = be % 24;
  const double* g = gatesT + (long)be * 6144;
  int ph = 0;

  unsigned long long key[24];
#pragma unroll
  for (int j = 0; j < 24; j++)
    key[j] = (unsigned long long)__double_as_longlong(g[tid + 256 * j]);

  // seed binary search with block min/max: lo = min-1, hi = max preserves the invariant
  // count(>lo) >= 1024 > count(>hi).
  unsigned long long mn = key[0], mx = key[0];
#pragma unroll
  for (int j = 1; j < 24; j++){
    mn = key[j] < mn ? key[j] : mn;
    mx = key[j] > mx ? key[j] : mx;
  }
#pragma unroll
  for (int off = 32; off > 0; off >>= 1){
    unsigned long long a = (unsigned long long)__shfl_down((long long)mn, off);
    unsigned long long c = (unsigned long long)__shfl_down((long long)mx, off);
    mn = a < mn ? a : mn;
    mx = c > mx ? c : mx;
  }
  if ((tid & 63) == 0){ mm[(tid >> 6) * 2] = mn; mm[(tid >> 6) * 2 + 1] = mx; }
  __syncthreads();
  mn = mm[0]; mx = mm[1];
#pragma unroll
  for (int q = 1; q < 4; q++){
    mn = mm[2 * q] < mn ? mm[2 * q] : mn;
    mx = mm[2 * q + 1] > mx ? mm[2 * q + 1] : mx;
  }

  unsigned long long lo = mn - 1ull, hi = mx;
  for (int it = 0; it < 64; ++it){
    if (hi - lo <= 1ull) break;
    unsigned long long mid = lo + ((hi - lo) >> 1);
    int c = 0;
#pragma unroll
    for (int j = 0; j < 24; j++) c += (key[j] > mid) ? 1 : 0;
    c = blk_reduce(c, sbuf, tid, ph++);
    if (c >= 1024) lo = mid; else hi = mid;
  }
  const unsigned long long T = hi;
  int cg = 0;
#pragma unroll
  for (int j = 0; j < 24; j++) cg += (key[j] > T) ? 1 : 0;
  cg = blk_reduce(cg, sbuf, tid, ph++);
  const int need = 1024 - cg;

  int lo2 = 0, hi2 = 6144;
  for (int it = 0; it < 13; ++it){
    if (hi2 - lo2 <= 1) break;
    int mid = (lo2 + hi2) >> 1;
    int c = 0;
#pragma unroll
    for (int j = 0; j < 24; j++) c += (key[j] == T && (tid + 256 * j) < mid) ? 1 : 0;
    c = blk_reduce(c, sbuf, tid, ph++);
    if (c >= need) hi2 = mid; else lo2 = mid;
  }
  const int m = hi2;

  if (tid == 0) s_pos = 0;
  __syncthreads();
#pragma unroll
  for (int j = 0; j < 24; j++){
    int n = tid + 256 * j;
    bool sel = (key[j] > T) || (key[j] == T && n < m);
    if (sel){
      int slot = atomicAdd(&s_pos, 1);
      Kidx[(long)be * 1024 + slot] = n;
      Gval[(long)be * 1024 + slot] = (float)__longlong_as_double((long long)key[j]);
      int t = b * 6144 + n;
      int p = atomicAdd(&cnt[t], 1);
      inv[(long)t * 24 + p] = (unsigned short)(e * 1024 + slot);
    }
  }
}

// -------- merge GEMM (fp32 out) -----------------------------------------------------------
__global__ __launch_bounds__(256, 2) void k_gemm2(const unsigned short* __restrict__ A,
    const unsigned short* __restrict__ BT, float* __restrict__ Cf)
{
  __shared__ unsigned short As[128 * 64];
  __shared__ unsigned short Bs[128 * 64];
  gemm_body<1>(A, BT, nullptr, Cf, 768, 768, As, Bs,
               (int)blockIdx.x * 128, (int)blockIdx.y * 128, (int)threadIdx.x);
}

// -------- fused per-expert FFN: Y[be][k][dh] = gate * (silu(gather(x1)@w1) @ w2), bf16 ----
// grid (16 m-tiles of 64 rows, 192 be). block 256. A-tile in registers (16 VGPR/lane).
// LDS 40960 B exactly -> 4 blocks/CU (160 KiB); launch_bounds(256,4) keeps VGPR <= 128.
// R4 structure, measured 70-71 us; established local optimum (R5-R8). FROZEN.
__global__ __launch_bounds__(256, 4) void k_ffn(const unsigned short* __restrict__ x1,
    const unsigned short* __restrict__ w1T, const unsigned short* __restrict__ w2T,
    const int* __restrict__ KidxAll, const float* __restrict__ GvalAll,
    unsigned short* __restrict__ Y)
{
  __shared__ unsigned short W1c[64 * 128];   // 16 KB [hcol][k]
  __shared__ unsigned short W2c[128 * 64];   // 16 KB [out][hchunk]
  __shared__ unsigned short Hc[64 * 64];     //  8 KB [tokrow][hcol]
  const int tid = threadIdx.x, lane = tid & 63, w = tid >> 6;
  const int tx = lane & 15, quad = lane >> 4;
  const int mt = blockIdx.x;                 // 0..15, 64-token tiles
  const int be = blockIdx.y;
  const int b = be / 24, e = be % 24;
  const int* idx = KidxAll + (long)be * 1024 + mt * 64;
  const float* scl = GvalAll + (long)be * 1024 + mt * 64;
  const unsigned short* A   = x1  + (long)b * 6144 * 128;
  const unsigned short* w1e = w1T + (long)e * 384 * 128;
  const unsigned short* w2e = w2T + (long)e * 128 * 384;

  // A-fragments direct to registers: afr[ks] = A[idx[w*16+tx]][ks*32+quad*8 ..+8]
  short8 afr[4];
  {
    const int r0 = idx[w * 16 + tx];
    const unsigned short* a0 = A + (long)r0 * 128 + quad * 8;
#pragma unroll
    for (int ks = 0; ks < 4; ks++) afr[ks] = *(const short8*)(a0 + ks * 32);
  }

  floatx4 Yt[2][4];   // [mf out-tile][nf tokrow-tile]
  {
    floatx4 z4 = {0.f, 0.f, 0.f, 0.f};
#pragma unroll
    for (int i = 0; i < 2; i++)
#pragma unroll
      for (int j = 0; j < 4; j++) Yt[i][j] = z4;
  }

  for (int nc = 0; nc < 6; ++nc){
    {
      const int r0 = w * 16;
#pragma unroll
      for (int i = 0; i < 4; i++){
        int lr = r0 + i * 4 + quad;
        int c = tx ^ (lr & 15);
        gll16(w1e + (long)(nc * 64 + lr) * 128 + c * 8, &W1c[(r0 + i * 4) * 128], lane);
      }
    }
    {
      const int r0 = w * 32;
#pragma unroll
      for (int i = 0; i < 4; i++){
        int rr = r0 + i * 8 + (lane >> 3);
        int c = (lane & 7) ^ (rr & 7);
        gll16(w2e + (long)rr * 384 + nc * 64 + c * 8, &W2c[(r0 + i * 8) * 64], lane);
      }
    }
    __syncthreads();

    // stage1: h = silu(A_regs @ W1c^T); wave w -> rows w*16..+16 x 64 hcols (4 nf)
    floatx4 h4[4];
    {
      floatx4 z4 = {0.f, 0.f, 0.f, 0.f};
#pragma unroll
      for (int j = 0; j < 4; j++) h4[j] = z4;
    }
#pragma unroll
    for (int ks = 0; ks < 4; ++ks){
      const int chunk = ks * 4 + quad;
      const int pos = chunk ^ tx;
#pragma unroll
      for (int nf = 0; nf < 4; ++nf){
        short8 bfr = *(const short8*)&W1c[(nf * 16 + tx) * 128 + pos * 8];
        h4[nf] = __builtin_amdgcn_mfma_f32_16x16x32_bf16(afr[ks], bfr, h4[nf], 0, 0, 0);
      }
    }
#pragma unroll
    for (int nf = 0; nf < 4; ++nf){
      const int hchunk = nf * 2 + (tx >> 3);
      const int hoff = tx & 7;
#pragma unroll
      for (int r = 0; r < 4; r++){
        float v = silu(h4[nf][r]);
        const int trow = w * 16 + quad * 4 + r;
        Hc[trow * 64 + (hchunk ^ (trow & 7)) * 8 + hoff] = f2bf(v);
      }
    }
    __syncthreads();

    // stage2: YT[out][tokrow] += W2c[out][hcol] x Hc[tokrow][hcol]; wave w -> outs w*32..+32
#pragma unroll
    for (int ks = 0; ks < 2; ++ks){
      const int chunk2 = ks * 4 + quad;
      const int posx = chunk2 ^ (tx & 7);
      short8 a2[2], b2[4];
#pragma unroll
      for (int mf = 0; mf < 2; ++mf)
        a2[mf] = *(const short8*)&W2c[(w * 32 + mf * 16 + tx) * 64 + posx * 8];
#pragma unroll
      for (int nf = 0; nf < 4; ++nf)
        b2[nf] = *(const short8*)&Hc[(nf * 16 + tx) * 64 + posx * 8];
#pragma unroll
      for (int mf = 0; mf < 2; ++mf)
#pragma unroll
        for (int nf = 0; nf < 4; ++nf)
          Yt[mf][nf] = __builtin_amdgcn_mfma_f32_16x16x32_bf16(a2[mf], b2[nf], Yt[mf][nf], 0, 0, 0);
    }
    __syncthreads();
  }

#pragma unroll
  for (int nf = 0; nf < 4; ++nf){
    const int rb = nf * 16 + tx;
    const float g = scl[rb];
    unsigned short* dst = Y + ((long)be * 1024 + mt * 64 + rb) * 128 + w * 32 + quad * 4;
#pragma unroll
    for (int mf = 0; mf < 2; ++mf){
      short4v v;
#pragma unroll
      for (int r = 0; r < 4; r++) v[r] = (short)f2bf(Yt[mf][nf][r] * g);
      *(short4v*)(dst + mf * 16) = v;
    }
  }
}

// -------- combine: xout[t][:] = sum over picks of Y[e][slot][:] (gates pre-applied) -------
// 4-way unrolled pick loop; inv codes loaded as one u64, Y-row dword loads issued
// independently (MLP) instead of the serial inv->Y dependent chain per pick.
__global__ __launch_bounds__(256) void k_combine(const int* __restrict__ cnt,
    const unsigned short* __restrict__ inv, const unsigned short* __restrict__ Y,
    unsigned short* __restrict__ xout)
{
  const int t = blockIdx.x * 4 + (threadIdx.x >> 6);   // token id, < 49152
  const int lane = threadIdx.x & 63;
  const int b = t / 6144;
  const int c = cnt[t];
  const unsigned short* ivp = inv + (long)t * 24;
  const unsigned short* Yb = Y + ((long)(b * 24) << 17);   // + code<<7 selects the row
  float a0 = 0.f, a1 = 0.f;
  int p = 0;
  for (; p + 4 <= c; p += 4){
    unsigned long long iv = *(const unsigned long long*)(ivp + p);   // t*48+2p: 8B-aligned
    const int c0 = (int)(iv & 0xffffu), c1 = (int)((iv >> 16) & 0xffffu);
    const int c2 = (int)((iv >> 32) & 0xffffu), c3 = (int)(iv >> 48);
    unsigned int v0 = *(const unsigned int*)(Yb + (((long)c0) << 7) + lane * 2);
    unsigned int v1 = *(const unsigned int*)(Yb + (((long)c1) << 7) + lane * 2);
    unsigned int v2 = *(const unsigned int*)(Yb + (((long)c2) << 7) + lane * 2);
    unsigned int v3 = *(const unsigned int*)(Yb + (((long)c3) << 7) + lane * 2);
    a0 += bf2f((unsigned short)v0); a1 += bf2f((unsigned short)(v0 >> 16));
    a0 += bf2f((unsigned short)v1); a1 += bf2f((unsigned short)(v1 >> 16));
    a0 += bf2f((unsigned short)v2); a1 += bf2f((unsigned short)(v2 >> 16));
    a0 += bf2f((unsigned short)v3); a1 += bf2f((unsigned short)(v3 >> 16));
  }
  for (; p < c; ++p){
    const int code = ivp[p];
    unsigned int v = *(const unsigned int*)(Yb + (((long)code) << 7) + lane * 2);
    a0 += bf2f((unsigned short)v); a1 += bf2f((unsigned short)(v >> 16));
  }
  unsigned short* o = xout + ((long)t << 7) + lane * 2;
  o[0] = f2bf(a0); o[1] = f2bf(a1);
}

// ==========================================================================================
extern "C" void kernel_launch(void* const* d_in, const int* in_sizes, int n_in,
                              void* d_out, int out_size, void* d_ws, size_t ws_size,
                              hipStream_t stream)
{
  const float* x      = (const float*)d_in[0];
  const float* choice = (const float*)d_in[1];
  const float* w1     = (const float*)d_in[2];
  const float* w2     = (const float*)d_in[3];
  const float* head   = (const float*)d_in[4];
  const float* merge  = (const float*)d_in[5];
  float* out = (float*)d_out;
  (void)in_sizes; (void)n_in; (void)out_size; (void)ws_size;

  char* p = (char*)d_ws;
  auto alloc = [&p](size_t bytes) -> void* {
    void* q = (void*)p; p += (bytes + 255) & ~(size_t)255; return q;
  };

  unsigned short* headT = (unsigned short*)alloc((size_t)768 * 768 * 2);
  unsigned short* mergeT= (unsigned short*)alloc((size_t)768 * 768 * 2);
  unsigned short* w1T   = (unsigned short*)alloc((size_t)24 * 384 * 128 * 2);
  unsigned short* w2T   = (unsigned short*)alloc((size_t)24 * 128 * 384 * 2);
  double* W64           = (double*)alloc((size_t)768 * 144 * 8);
  int* Kidx             = (int*)alloc((size_t)192 * 1024 * 4);
  float* Gval           = (float*)alloc((size_t)192 * 1024 * 4);
  int* cnt              = (int*)alloc((size_t)49152 * 4);
  unsigned short* inv   = (unsigned short*)alloc((size_t)49152 * 24 * 2);
  unsigned short* xb    = (unsigned short*)alloc((size_t)8192 * 768 * 2);   // 12.58 MB
  unsigned short* x1    = (unsigned short*)alloc((size_t)8192 * 768 * 2);   // 12.58 MB
  // big region (50.33 MB): Y for ffn; before topk it hosts P (37.75) + gatesT (9.44)
  unsigned short* Y     = (unsigned short*)alloc((size_t)192 * 1024 * 128 * 2);
  double* P             = (double*)Y;                                             // [4][8192][144]
  double* gatesT        = (double*)((char*)Y + (size_t)4 * 8192 * 144 * 8);       // 9.44 MB
  unsigned short* xout  = xb;            // xb dead after k_main0; xout written by combine
  // probe (516 B) aliases Kidx: written by k_prep, read by k_main0, dead before k_topk.
  unsigned int* probe   = (unsigned int*)Kidx;

  hipMemsetAsync(cnt, 0, (size_t)49152 * 4, stream);
  k_prep<<<dim3(7393), 256, 0, stream>>>(x, choice, w1, w2, head, merge,
                                         xb, headT, mergeT, w1T, w2T, W64, probe);
  k_main0<<<dim3(896), 256, 0, stream>>>(xb, headT, x1, x, W64, P, probe);
  k_softmax<<<dim3(192), 256, 0, stream>>>(P, gatesT);
  k_topk<<<dim3(192), 256, 0, stream>>>(gatesT, Kidx, Gval, cnt, inv);
  // P/gatesT dead; Y region free for ffn
  k_ffn<<<dim3(16, 192, 1), 256, 0, stream>>>(x1, w1T, w2T, Kidx, Gval, Y);
  k_combine<<<dim3(12288), 256, 0, stream>>>(cnt, inv, Y, xout);
  k_gemm2<<<dim3(64, 6, 1), 256, 0, stream>>>(xout, mergeT, out);
}

// Round 13
// 328.958 us; speedup vs baseline: 1.0624x; 1.0003x over previous
//
#include <hip/hip_runtime.h>
#include <stdint.h>
#include <math.h>

typedef __attribute__((ext_vector_type(8))) short short8;
typedef __attribute__((ext_vector_type(4))) short short4v;
typedef __attribute__((ext_vector_type(4))) float floatx4;
typedef __attribute__((ext_vector_type(2))) float floatx2;
typedef __attribute__((ext_vector_type(4))) double double4v;

#define DEV static __device__ __forceinline__

DEV float bf2f(unsigned short u){ union { unsigned int i; float f; } c; c.i = ((unsigned int)u) << 16; return c.f; }
// R13: native RTNE convert (gfx950 v_cvt_*bf16_f32, 1 VALU op) replaces 4-op bit-twiddle.
// Same round-to-nearest-even semantics -> bit-identical outputs.
DEV unsigned short f2bf(float f){
  union { __bf16 h; unsigned short u; } c;
  c.h = (__bf16)f;
  return c.u;
}

#if defined(__has_builtin)
#if __has_builtin(__builtin_amdgcn_global_load_lds)
#define USE_GLL 1
#endif
#if __has_builtin(__builtin_amdgcn_exp2f) && __has_builtin(__builtin_amdgcn_rcpf)
#define FAST_SILU 1
#endif
#endif
#ifndef USE_GLL
#define USE_GLL 0
#endif
#ifndef FAST_SILU
#define FAST_SILU 0
#endif

// async global->LDS, 16B per lane. ldsbase is wave-uniform; HW writes base + lane*16.
DEV void gll16(const unsigned short* g, unsigned short* ldsbase, int lane){
#if USE_GLL
  __builtin_amdgcn_global_load_lds((const __attribute__((address_space(1))) void*)g,
                                   (__attribute__((address_space(3))) void*)ldsbase, 16, 0, 0);
#else
  *(short8*)(ldsbase + lane * 8) = *(const short8*)g;
#endif
}

DEV float silu(float v){
#if FAST_SILU
  float ex = __builtin_amdgcn_exp2f(v * -1.44269504088896f);
  return v * __builtin_amdgcn_rcpf(1.f + ex);   // rcp err ~1ulp fp32, hidden by bf16 round
#else
  return v / (1.f + __expf(-v));
#endif
}

// -------- transpose tile helper: out_bf16[C][R] = in_f32[R][C] ----------------------------
DEV void transpose_tile(const float* in, unsigned short* out, int R, int C,
                        int bx, int by, int bz, int tid, unsigned short* tile)
{
  const long boff = (long)bz * (long)R * (long)C;
  in += boff; out += boff;
  const int c0 = bx * 64, r0 = by * 64;
  const int rr = tid >> 4;
  const int c4 = (tid & 15) * 4;
#pragma unroll
  for (int i = 0; i < 4; i++){
    int r = rr + i * 16;
    floatx4 v = *(const floatx4*)(in + (long)(r0 + r) * C + c0 + c4);
#pragma unroll
    for (int u = 0; u < 4; u++) tile[r * 68 + c4 + u] = f2bf(v[u]);
  }
  __syncthreads();
#pragma unroll
  for (int i = 0; i < 4; i++){
    int cc = rr + i * 16;
    short4v v;
#pragma unroll
    for (int u = 0; u < 4; u++) v[u] = (short)tile[(c4 + u) * 68 + cc];
    *(short4v*)(out + (long)(c0 + cc) * R + r0 + c4) = v;
  }
}

// -------- fused prep: 4 transposes + fold + xconv + f64-MFMA layout probe -----------------
__global__ __launch_bounds__(256) void k_prep(const float* __restrict__ x,
    const float* __restrict__ choice, const float* __restrict__ w1,
    const float* __restrict__ w2, const float* __restrict__ head,
    const float* __restrict__ merge,
    unsigned short* __restrict__ xb, unsigned short* __restrict__ headT,
    unsigned short* __restrict__ mergeT, unsigned short* __restrict__ w1T,
    unsigned short* __restrict__ w2T, double* __restrict__ W64,
    unsigned int* __restrict__ probe)
{
  __shared__ double buf[1536];   // 12.3 KB: transpose tile (8.7 KB) or fold hrow (12.3 KB)
  unsigned short* tile = (unsigned short*)buf;
  const int id = blockIdx.x, tid = threadIdx.x;
  if (id < 144){
    transpose_tile(head, headT, 768, 768, id % 12, id / 12, 0, tid, tile);
  } else if (id < 288){
    int l = id - 144;
    transpose_tile(merge, mergeT, 768, 768, l % 12, l / 12, 0, tid, tile);
  } else if (id < 576){
    int l = id - 288;
    transpose_tile(w1, w1T, 128, 384, l % 6, (l / 6) % 2, l / 12, tid, tile);
  } else if (id < 864){
    int l = id - 576;
    transpose_tile(w2, w2T, 384, 128, l % 2, (l / 2) % 6, l / 12, tid, tile);
  } else if (id < 1248){
    int l = id - 864;                       // 0..383, fold: 2 d's per block
    const int sub = tid >> 7, lt = tid & 127;
    const int d = l * 2 + sub;
    double* hrow = buf + sub * 768;
    for (int i = lt; i < 768; i += 128) hrow[i] = (double)head[(long)d * 768 + i];
    __syncthreads();
    for (int c = lt; c < 144; c += 128){
      int h = c / 24, e = c % 24;
      double a = 0.0;
      const double* hr = hrow + h * 128;
      const float* ch = choice + e * 128;
#pragma unroll 8
      for (int k = 0; k < 128; k++) a += hr[k] * (double)ch[k];
      W64[(long)d * 144 + c] = a;
    }
  } else if (id < 7392){
    const long l = id - 1248;               // 0..6143
    const long i = (l * 256 + tid) * 4;
    floatx4 v = *(const floatx4*)(x + i);
    short4v o;
#pragma unroll
    for (int u = 0; u < 4; u++) o[u] = (short)f2bf(v[u]);
    *(short4v*)(xb + i) = o;
  } else {
    // ---- f64 MFMA layout probe (1 wave). Layout-agnostic operands:
    // probe1: A-val = lane, B == 1  => D[i][j] = S_A(i) independent of j.
    //   A std (lane=16k+i): S_A = 96+4i (==0 mod 4). A alt (lane=4i+k): 16i+6 (==2 mod 4).
    // probe2: A == 1, B-val = lane  => D[i][j] = S_B(j) -> B flag + true D-col per lane.
    if (tid < 64){
      double4v z = {0.0, 0.0, 0.0, 0.0};
      double4v d1 = __builtin_amdgcn_mfma_f64_16x16x4f64((double)tid, 1.0, z, 0, 0, 0);
      double4v d2 = __builtin_amdgcn_mfma_f64_16x16x4f64(1.0, (double)tid, z, 0, 0, 0);
      const int V0 = (int)d1[0];
      const int Astd = ((V0 & 3) == 0) ? 1 : 0;
      unsigned int rp = 0;
      int V;
      V = (int)d1[0]; rp |= (unsigned int)(Astd ? (V - 96) >> 2 : (V - 6) >> 4);
      V = (int)d1[1]; rp |= (unsigned int)(Astd ? (V - 96) >> 2 : (V - 6) >> 4) << 8;
      V = (int)d1[2]; rp |= (unsigned int)(Astd ? (V - 96) >> 2 : (V - 6) >> 4) << 16;
      V = (int)d1[3]; rp |= (unsigned int)(Astd ? (V - 96) >> 2 : (V - 6) >> 4) << 24;
      const int W0 = (int)d2[0];
      const int Bstd = ((W0 & 3) == 0) ? 1 : 0;
      const int cl = Bstd ? (W0 - 96) >> 2 : (W0 - 6) >> 4;
      probe[tid] = rp;
      probe[64 + tid] = (unsigned int)cl;
      if (tid == 0) probe[128] = (unsigned int)(Astd | (Bstd << 1));
    }
  }
}

// -------- bf16 MFMA GEMM body (BT input), 128x128 tile, BK=64; OUTF=1 -> fp32 C -----------
template<int OUTF>
DEV void gemm_body(const unsigned short* __restrict__ A, const unsigned short* __restrict__ BT,
                   unsigned short* __restrict__ C, float* __restrict__ Cf, int N, int K,
                   unsigned short* As, unsigned short* Bs, int m0, int n0, int tid)
{
  const int lane = tid & 63;
  const int w = tid >> 6;
  const int wy = w >> 1, wx = w & 1;

  floatx4 acc[4][4];
  {
    floatx4 z4 = {0.f, 0.f, 0.f, 0.f};
#pragma unroll
    for (int i = 0; i < 4; i++)
#pragma unroll
      for (int j = 0; j < 4; j++) acc[i][j] = z4;
  }

  const int rsub = lane >> 3;
  const int kcol = (lane & 7) * 8;

  for (int k0 = 0; k0 < K; k0 += 64){
#pragma unroll
    for (int i = 0; i < 4; i++){
      const int inst = w * 4 + i;
      const int rr = inst * 8 + rsub;
      gll16(A + (long)(m0 + rr) * K + k0 + kcol, &As[inst * 512], lane);
      gll16(BT + (long)(n0 + rr) * K + k0 + kcol, &Bs[inst * 512], lane);
    }
    __syncthreads();
#pragma unroll
    for (int ks = 0; ks < 2; ++ks){
      const int kb = ks * 32 + (lane >> 4) * 8;
      short8 af[4], bfr[4];
#pragma unroll
      for (int mi = 0; mi < 4; mi++) af[mi]  = *(const short8*)&As[(wy * 64 + mi * 16 + (lane & 15)) * 64 + kb];
#pragma unroll
      for (int ni = 0; ni < 4; ni++) bfr[ni] = *(const short8*)&Bs[(wx * 64 + ni * 16 + (lane & 15)) * 64 + kb];
#pragma unroll
      for (int mi = 0; mi < 4; mi++)
#pragma unroll
        for (int ni = 0; ni < 4; ni++)
          acc[mi][ni] = __builtin_amdgcn_mfma_f32_16x16x32_bf16(af[mi], bfr[ni], acc[mi][ni], 0, 0, 0);
    }
    __syncthreads();
  }

  const int ml = lane & 15;
  const int rq = (lane >> 4) * 4;
#pragma unroll
  for (int mi = 0; mi < 4; mi++){
    const int rowb = m0 + wy * 64 + mi * 16 + rq;
#pragma unroll
    for (int ni = 0; ni < 4; ni++){
      const int col = n0 + wx * 64 + ni * 16 + ml;
#pragma unroll
      for (int r = 0; r < 4; r++){
        float v = acc[mi][ni][r];
        if (OUTF) Cf[(long)(rowb + r) * N + col] = v;
        else      C[(long)(rowb + r) * N + col] = f2bf(v);
      }
    }
  }
}

// -------- gates via fp64 MFMA, probe-calibrated layouts; 4 K-segments of 192 --------------
// K remap for vector A-loads: for each 16-K block, instruction i (i=0..3) takes global
// k = k0 + slot*4 + i (slot = probed ak for A-lane, bk for B-lane; same sigma on both sides,
// covers all 16 k's exactly once) -> lane loads ONE float4 per 16 K instead of 4 scalars.
DEV void gates_mfma(const float* __restrict__ xg, const double* __restrict__ W,
                    double* __restrict__ P, const unsigned int* __restrict__ probe,
                    int id, int tid)
{
  const int lane = tid & 63, w = tid >> 6;
  const unsigned int flags = probe[128];
  const int Astd = (int)(flags & 1u), Bstd = (int)((flags >> 1) & 1u);
  const unsigned int rp = probe[lane];
  const int cl = (int)probe[64 + lane];
  const int ar = Astd ? (lane & 15) : (lane >> 2);   // A row this lane supplies
  const int ak = Astd ? (lane >> 4) : (lane & 3);    // A k-slot this lane supplies
  const int bk = Bstd ? (lane >> 4) : (lane & 3);    // B k-slot
  const int bj = Bstd ? (lane & 15) : (lane >> 2);   // B col-in-tile

  const int kseg = id >> 7;            // 0..3 K-segments of 192
  const int row0 = (id & 127) * 64 + w * 16;

  double4v acc[9];
#pragma unroll
  for (int t = 0; t < 9; t++) acc[t] = (double4v){0.0, 0.0, 0.0, 0.0};

  const float* arow = xg + (long)(row0 + ar) * 768;
  const int kbase = kseg * 192;
  for (int kb = 0; kb < 192; kb += 16){
    const int k0 = kbase + kb;
    floatx4 av = *(const floatx4*)(arow + k0 + ak * 4);
#pragma unroll
    for (int i = 0; i < 4; i++){
      const double a = (double)av[i];
      const double* wr = W + (long)(k0 + bk * 4 + i) * 144 + bj;
#pragma unroll
      for (int t = 0; t < 9; t++)
        acc[t] = __builtin_amdgcn_mfma_f64_16x16x4f64(a, wr[t * 16], acc[t], 0, 0, 0);
    }
  }

  const int r0_ = (int)(rp & 255u), r1_ = (int)((rp >> 8) & 255u);
  const int r2_ = (int)((rp >> 16) & 255u), r3_ = (int)((rp >> 24) & 255u);
  double* dst = P + (long)kseg * 8192 * 144 + (long)row0 * 144;
#pragma unroll
  for (int t = 0; t < 9; t++){
    const int cb = t * 16 + cl;
    dst[(long)r0_ * 144 + cb] = acc[t][0];
    dst[(long)r1_ * 144 + cb] = acc[t][1];
    dst[(long)r2_ * 144 + cb] = acc[t][2];
    dst[(long)r3_ * 144 + cb] = acc[t][3];
  }
}

// -------- fused gates + head-GEMM: [0,512) fp64-MFMA gates, [512,896) bf16 gemm -----------
__global__ __launch_bounds__(256, 4) void k_main0(const unsigned short* __restrict__ xb,
    const unsigned short* __restrict__ headT, unsigned short* __restrict__ x1,
    const float* __restrict__ xg, const double* __restrict__ W, double* __restrict__ P,
    const unsigned int* __restrict__ probe)
{
  __shared__ unsigned short lds[128 * 64 * 2];   // 32 KB: gemm As+Bs; gates uses none
  const int id = blockIdx.x, tid = threadIdx.x;
  if (id < 512){
    gates_mfma(xg, W, P, probe, id, tid);
  } else {
    const int id2 = id - 512;    // 0..383
    unsigned short* As = lds;
    unsigned short* Bs = As + 128 * 64;
    gemm_body<0>(xb, headT, x1, nullptr, 768, 768, As, Bs, (id2 & 63) * 128, (id2 >> 6) * 128, tid);
  }
}

// -------- fused reduce + softmax: logits from 4 partials, softmax, write gatesT[be][n] ----
__global__ __launch_bounds__(256) void k_softmax(const double* __restrict__ P,
                                                 double* __restrict__ gatesT)
{
  const int gid = blockIdx.x * 256 + threadIdx.x;   // < 49152
  const int R = gid / 6, h = gid % 6;
  const int b = R >> 10, s = R & 1023;
  const int n = s * 6 + h;
  const long S = (long)8192 * 144;
  const long base = (long)R * 144 + h * 24;
  double l[24];
#pragma unroll
  for (int e = 0; e < 24; e++){
    const long o = base + e;
    l[e] = (P[o] + P[S + o]) + (P[2 * S + o] + P[3 * S + o]);
  }
  double m = l[0];
#pragma unroll
  for (int e = 1; e < 24; e++) m = fmax(m, l[e]);
  double ssum = 0.0;
#pragma unroll
  for (int e = 0; e < 24; e++){ l[e] = exp(l[e] - m); ssum += l[e]; }
  double is = 1.0 / ssum;
#pragma unroll
  for (int e = 0; e < 24; e++)
    gatesT[((long)(b * 24 + e)) * 6144 + n] = l[e] * is;
}

// -------- top-K=1024 of 6144 per (b,e), exact fp64, jax tie semantics ---------------------
// Single-barrier block reduce via parity double-buffer (round k+2's write to buf p can
// only happen after round k+1's sync, which waits for all round-k readers of buf p).
DEV int blk_reduce(int v, volatile int* sbuf, int tid, int ph){
#pragma unroll
  for (int off = 32; off > 0; off >>= 1) v += __shfl_down(v, off);
  volatile int* sb = sbuf + (ph & 1) * 4;
  if ((tid & 63) == 0) sb[tid >> 6] = v;
  __syncthreads();
  return sb[0] + sb[1] + sb[2] + sb[3];
}

__global__ __launch_bounds__(256) void k_topk(const double* __restrict__ gatesT,
                                              int* __restrict__ Kidx, float* __restrict__ Gval,
                                              int* __restrict__ cnt, unsigned short* __restrict__ inv)
{
  __shared__ int sbuf[8];
  __shared__ int s_pos;
  __shared__ unsigned long long mm[8];
  const int tid = threadIdx.x;
  const int be = blockIdx.x;
  const int b = be / 24, e = be % 24;
  const double* g = gatesT + (long)be * 6144;
  int ph = 0;

  unsigned long long key[24];
#pragma unroll
  for (int j = 0; j < 24; j++)
    key[j] = (unsigned long long)__double_as_longlong(g[tid + 256 * j]);

  // seed binary search with block min/max: lo = min-1, hi = max preserves the invariant
  // count(>lo) >= 1024 > count(>hi).
  unsigned long long mn = key[0], mx = key[0];
#pragma unroll
  for (int j = 1; j < 24; j++){
    mn = key[j] < mn ? key[j] : mn;
    mx = key[j] > mx ? key[j] : mx;
  }
#pragma unroll
  for (int off = 32; off > 0; off >>= 1){
    unsigned long long a = (unsigned long long)__shfl_down((long long)mn, off);
    unsigned long long c = (unsigned long long)__shfl_down((long long)mx, off);
    mn = a < mn ? a : mn;
    mx = c > mx ? c : mx;
  }
  if ((tid & 63) == 0){ mm[(tid >> 6) * 2] = mn; mm[(tid >> 6) * 2 + 1] = mx; }
  __syncthreads();
  mn = mm[0]; mx = mm[1];
#pragma unroll
  for (int q = 1; q < 4; q++){
    mn = mm[2 * q] < mn ? mm[2 * q] : mn;
    mx = mm[2 * q + 1] > mx ? mm[2 * q + 1] : mx;
  }

  unsigned long long lo = mn - 1ull, hi = mx;
  for (int it = 0; it < 64; ++it){
    if (hi - lo <= 1ull) break;
    unsigned long long mid = lo + ((hi - lo) >> 1);
    int c = 0;
#pragma unroll
    for (int j = 0; j < 24; j++) c += (key[j] > mid) ? 1 : 0;
    c = blk_reduce(c, sbuf, tid, ph++);
    if (c >= 1024) lo = mid; else hi = mid;
  }
  const unsigned long long T = hi;
  int cg = 0;
#pragma unroll
  for (int j = 0; j < 24; j++) cg += (key[j] > T) ? 1 : 0;
  cg = blk_reduce(cg, sbuf, tid, ph++);
  const int need = 1024 - cg;

  int lo2 = 0, hi2 = 6144;
  for (int it = 0; it < 13; ++it){
    if (hi2 - lo2 <= 1) break;
    int mid = (lo2 + hi2) >> 1;
    int c = 0;
#pragma unroll
    for (int j = 0; j < 24; j++) c += (key[j] == T && (tid + 256 * j) < mid) ? 1 : 0;
    c = blk_reduce(c, sbuf, tid, ph++);
    if (c >= need) hi2 = mid; else lo2 = mid;
  }
  const int m = hi2;

  if (tid == 0) s_pos = 0;
  __syncthreads();
#pragma unroll
  for (int j = 0; j < 24; j++){
    int n = tid + 256 * j;
    bool sel = (key[j] > T) || (key[j] == T && n < m);
    if (sel){
      int slot = atomicAdd(&s_pos, 1);
      Kidx[(long)be * 1024 + slot] = n;
      Gval[(long)be * 1024 + slot] = (float)__longlong_as_double((long long)key[j]);
      int t = b * 6144 + n;
      int p = atomicAdd(&cnt[t], 1);
      inv[(long)t * 24 + p] = (unsigned short)(e * 1024 + slot);
    }
  }
}

// -------- merge GEMM (fp32 out) -----------------------------------------------------------
__global__ __launch_bounds__(256, 2) void k_gemm2(const unsigned short* __restrict__ A,
    const unsigned short* __restrict__ BT, float* __restrict__ Cf)
{
  __shared__ unsigned short As[128 * 64];
  __shared__ unsigned short Bs[128 * 64];
  gemm_body<1>(A, BT, nullptr, Cf, 768, 768, As, Bs,
               (int)blockIdx.x * 128, (int)blockIdx.y * 128, (int)threadIdx.x);
}

// -------- fused per-expert FFN: Y[be][k][dh] = gate * (silu(gather(x1)@w1) @ w2), bf16 ----
// grid (16 m-tiles of 64 rows, 192 be). block 256. A-tile in registers (16 VGPR/lane).
// LDS 40960 B exactly -> 4 blocks/CU (160 KiB); launch_bounds(256,4) keeps VGPR <= 128.
// R4 structure, measured 70-71 us; established local optimum (R5-R8). FROZEN except f2bf.
__global__ __launch_bounds__(256, 4) void k_ffn(const unsigned short* __restrict__ x1,
    const unsigned short* __restrict__ w1T, const unsigned short* __restrict__ w2T,
    const int* __restrict__ KidxAll, const float* __restrict__ GvalAll,
    unsigned short* __restrict__ Y)
{
  __shared__ unsigned short W1c[64 * 128];   // 16 KB [hcol][k]
  __shared__ unsigned short W2c[128 * 64];   // 16 KB [out][hchunk]
  __shared__ unsigned short Hc[64 * 64];     //  8 KB [tokrow][hcol]
  const int tid = threadIdx.x, lane = tid & 63, w = tid >> 6;
  const int tx = lane & 15, quad = lane >> 4;
  const int mt = blockIdx.x;                 // 0..15, 64-token tiles
  const int be = blockIdx.y;
  const int b = be / 24, e = be % 24;
  const int* idx = KidxAll + (long)be * 1024 + mt * 64;
  const float* scl = GvalAll + (long)be * 1024 + mt * 64;
  const unsigned short* A   = x1  + (long)b * 6144 * 128;
  const unsigned short* w1e = w1T + (long)e * 384 * 128;
  const unsigned short* w2e = w2T + (long)e * 128 * 384;

  // A-fragments direct to registers: afr[ks] = A[idx[w*16+tx]][ks*32+quad*8 ..+8]
  short8 afr[4];
  {
    const int r0 = idx[w * 16 + tx];
    const unsigned short* a0 = A + (long)r0 * 128 + quad * 8;
#pragma unroll
    for (int ks = 0; ks < 4; ks++) afr[ks] = *(const short8*)(a0 + ks * 32);
  }

  floatx4 Yt[2][4];   // [mf out-tile][nf tokrow-tile]
  {
    floatx4 z4 = {0.f, 0.f, 0.f, 0.f};
#pragma unroll
    for (int i = 0; i < 2; i++)
#pragma unroll
      for (int j = 0; j < 4; j++) Yt[i][j] = z4;
  }

  for (int nc = 0; nc < 6; ++nc){
    {
      const int r0 = w * 16;
#pragma unroll
      for (int i = 0; i < 4; i++){
        int lr = r0 + i * 4 + quad;
        int c = tx ^ (lr & 15);
        gll16(w1e + (long)(nc * 64 + lr) * 128 + c * 8, &W1c[(r0 + i * 4) * 128], lane);
      }
    }
    {
      const int r0 = w * 32;
#pragma unroll
      for (int i = 0; i < 4; i++){
        int rr = r0 + i * 8 + (lane >> 3);
        int c = (lane & 7) ^ (rr & 7);
        gll16(w2e + (long)rr * 384 + nc * 64 + c * 8, &W2c[(r0 + i * 8) * 64], lane);
      }
    }
    __syncthreads();

    // stage1: h = silu(A_regs @ W1c^T); wave w -> rows w*16..+16 x 64 hcols (4 nf)
    floatx4 h4[4];
    {
      floatx4 z4 = {0.f, 0.f, 0.f, 0.f};
#pragma unroll
      for (int j = 0; j < 4; j++) h4[j] = z4;
    }
#pragma unroll
    for (int ks = 0; ks < 4; ++ks){
      const int chunk = ks * 4 + quad;
      const int pos = chunk ^ tx;
#pragma unroll
      for (int nf = 0; nf < 4; ++nf){
        short8 bfr = *(const short8*)&W1c[(nf * 16 + tx) * 128 + pos * 8];
        h4[nf] = __builtin_amdgcn_mfma_f32_16x16x32_bf16(afr[ks], bfr, h4[nf], 0, 0, 0);
      }
    }
#pragma unroll
    for (int nf = 0; nf < 4; ++nf){
      const int hchunk = nf * 2 + (tx >> 3);
      const int hoff = tx & 7;
#pragma unroll
      for (int r = 0; r < 4; r++){
        float v = silu(h4[nf][r]);
        const int trow = w * 16 + quad * 4 + r;
        Hc[trow * 64 + (hchunk ^ (trow & 7)) * 8 + hoff] = f2bf(v);
      }
    }
    __syncthreads();

    // stage2: YT[out][tokrow] += W2c[out][hcol] x Hc[tokrow][hcol]; wave w -> outs w*32..+32
#pragma unroll
    for (int ks = 0; ks < 2; ++ks){
      const int chunk2 = ks * 4 + quad;
      const int posx = chunk2 ^ (tx & 7);
      short8 a2[2], b2[4];
#pragma unroll
      for (int mf = 0; mf < 2; ++mf)
        a2[mf] = *(const short8*)&W2c[(w * 32 + mf * 16 + tx) * 64 + posx * 8];
#pragma unroll
      for (int nf = 0; nf < 4; ++nf)
        b2[nf] = *(const short8*)&Hc[(nf * 16 + tx) * 64 + posx * 8];
#pragma unroll
      for (int mf = 0; mf < 2; ++mf)
#pragma unroll
        for (int nf = 0; nf < 4; ++nf)
          Yt[mf][nf] = __builtin_amdgcn_mfma_f32_16x16x32_bf16(a2[mf], b2[nf], Yt[mf][nf], 0, 0, 0);
    }
    __syncthreads();
  }

#pragma unroll
  for (int nf = 0; nf < 4; ++nf){
    const int rb = nf * 16 + tx;
    const float g = scl[rb];
    unsigned short* dst = Y + ((long)be * 1024 + mt * 64 + rb) * 128 + w * 32 + quad * 4;
#pragma unroll
    for (int mf = 0; mf < 2; ++mf){
      short4v v;
#pragma unroll
      for (int r = 0; r < 4; r++) v[r] = (short)f2bf(Yt[mf][nf][r] * g);
      *(short4v*)(dst + mf * 16) = v;
    }
  }
}

// -------- combine: xout[t][:] = sum over picks of Y[e][slot][:] (gates pre-applied) -------
// 4-way unrolled pick loop; inv codes loaded as one u64, Y-row dword loads issued
// independently (MLP) instead of the serial inv->Y dependent chain per pick.
__global__ __launch_bounds__(256) void k_combine(const int* __restrict__ cnt,
    const unsigned short* __restrict__ inv, const unsigned short* __restrict__ Y,
    unsigned short* __restrict__ xout)
{
  const int t = blockIdx.x * 4 + (threadIdx.x >> 6);   // token id, < 49152
  const int lane = threadIdx.x & 63;
  const int b = t / 6144;
  const int c = cnt[t];
  const unsigned short* ivp = inv + (long)t * 24;
  const unsigned short* Yb = Y + ((long)(b * 24) << 17);   // + code<<7 selects the row
  float a0 = 0.f, a1 = 0.f;
  int p = 0;
  for (; p + 4 <= c; p += 4){
    unsigned long long iv = *(const unsigned long long*)(ivp + p);   // t*48+2p: 8B-aligned
    const int c0 = (int)(iv & 0xffffu), c1 = (int)((iv >> 16) & 0xffffu);
    const int c2 = (int)((iv >> 32) & 0xffffu), c3 = (int)(iv >> 48);
    unsigned int v0 = *(const unsigned int*)(Yb + (((long)c0) << 7) + lane * 2);
    unsigned int v1 = *(const unsigned int*)(Yb + (((long)c1) << 7) + lane * 2);
    unsigned int v2 = *(const unsigned int*)(Yb + (((long)c2) << 7) + lane * 2);
    unsigned int v3 = *(const unsigned int*)(Yb + (((long)c3) << 7) + lane * 2);
    a0 += bf2f((unsigned short)v0); a1 += bf2f((unsigned short)(v0 >> 16));
    a0 += bf2f((unsigned short)v1); a1 += bf2f((unsigned short)(v1 >> 16));
    a0 += bf2f((unsigned short)v2); a1 += bf2f((unsigned short)(v2 >> 16));
    a0 += bf2f((unsigned short)v3); a1 += bf2f((unsigned short)(v3 >> 16));
  }
  for (; p < c; ++p){
    const int code = ivp[p];
    unsigned int v = *(const unsigned int*)(Yb + (((long)code) << 7) + lane * 2);
    a0 += bf2f((unsigned short)v); a1 += bf2f((unsigned short)(v >> 16));
  }
  unsigned short* o = xout + ((long)t << 7) + lane * 2;
  o[0] = f2bf(a0); o[1] = f2bf(a1);
}

// ==========================================================================================
extern "C" void kernel_launch(void* const* d_in, const int* in_sizes, int n_in,
                              void* d_out, int out_size, void* d_ws, size_t ws_size,
                              hipStream_t stream)
{
  const float* x      = (const float*)d_in[0];
  const float* choice = (const float*)d_in[1];
  const float* w1     = (const float*)d_in[2];
  const float* w2     = (const float*)d_in[3];
  const float* head   = (const float*)d_in[4];
  const float* merge  = (const float*)d_in[5];
  float* out = (float*)d_out;
  (void)in_sizes; (void)n_in; (void)out_size; (void)ws_size;

  char* p = (char*)d_ws;
  auto alloc = [&p](size_t bytes) -> void* {
    void* q = (void*)p; p += (bytes + 255) & ~(size_t)255; return q;
  };

  unsigned short* headT = (unsigned short*)alloc((size_t)768 * 768 * 2);
  unsigned short* mergeT= (unsigned short*)alloc((size_t)768 * 768 * 2);
  unsigned short* w1T   = (unsigned short*)alloc((size_t)24 * 384 * 128 * 2);
  unsigned short* w2T   = (unsigned short*)alloc((size_t)24 * 128 * 384 * 2);
  double* W64           = (double*)alloc((size_t)768 * 144 * 8);
  int* Kidx             = (int*)alloc((size_t)192 * 1024 * 4);
  float* Gval           = (float*)alloc((size_t)192 * 1024 * 4);
  int* cnt              = (int*)alloc((size_t)49152 * 4);
  unsigned short* inv   = (unsigned short*)alloc((size_t)49152 * 24 * 2);
  unsigned short* xb    = (unsigned short*)alloc((size_t)8192 * 768 * 2);   // 12.58 MB
  unsigned short* x1    = (unsigned short*)alloc((size_t)8192 * 768 * 2);   // 12.58 MB
  // big region (50.33 MB): Y for ffn; before topk it hosts P (37.75) + gatesT (9.44)
  unsigned short* Y     = (unsigned short*)alloc((size_t)192 * 1024 * 128 * 2);
  double* P             = (double*)Y;                                             // [4][8192][144]
  double* gatesT        = (double*)((char*)Y + (size_t)4 * 8192 * 144 * 8);       // 9.44 MB
  unsigned short* xout  = xb;            // xb dead after k_main0; xout written by combine
  // probe (516 B) aliases Kidx: written by k_prep, read by k_main0, dead before k_topk.
  unsigned int* probe   = (unsigned int*)Kidx;

  hipMemsetAsync(cnt, 0, (size_t)49152 * 4, stream);
  k_prep<<<dim3(7393), 256, 0, stream>>>(x, choice, w1, w2, head, merge,
                                         xb, headT, mergeT, w1T, w2T, W64, probe);
  k_main0<<<dim3(896), 256, 0, stream>>>(xb, headT, x1, x, W64, P, probe);
  k_softmax<<<dim3(192), 256, 0, stream>>>(P, gatesT);
  k_topk<<<dim3(192), 256, 0, stream>>>(gatesT, Kidx, Gval, cnt, inv);
  // P/gatesT dead; Y region free for ffn
  k_ffn<<<dim3(16, 192, 1), 256, 0, stream>>>(x1, w1T, w2T, Kidx, Gval, Y);
  k_combine<<<dim3(12288), 256, 0, stream>>>(cnt, inv, Y, xout);
  k_gemm2<<<dim3(64, 6, 1), 256, 0, stream>>>(xout, mergeT, out);
}